// Round 12
// baseline (452.003 us; speedup 1.0000x reference)
//
#include <hip/hip_runtime.h>
#include <math.h>

#define NN   20000
#define EE   320000
#define ETOT 340000
#define FIN  128
#define HH   4
#define CC   64
#define HC   256
#define GG   64
#define BN_EPS 1e-5f
#define S1   384   // BcatT1 cols: 256 (W1 perm) + 64 (Wskip) + 8 (es/ed) + 56 pad
#define S2   320   // BcatT2 cols: 256 (W2 perm) + 8 (es/ed) + 56 pad

typedef _Float16 v8h __attribute__((ext_vector_type(8)));
typedef float    v4f __attribute__((ext_vector_type(4)));

__device__ __forceinline__ unsigned short f2bf(float f) {
    unsigned u = __float_as_uint(f);
    unsigned r = (u + 0x7FFF + ((u >> 16) & 1)) >> 16;   // RNE
    return (unsigned short)r;
}
__device__ __forceinline__ float bf2f(unsigned short u) {
    return __uint_as_float((unsigned)u << 16);
}
__device__ __forceinline__ float gelu_exact(float v) {
    return 0.5f * v * (1.f + erff(v * 0.70710678118654752f));
}

// ====== pre1: gbound | BcatT1 | BcatT2 | count+epos | zero d_out ==================
// blocks [0,79): gbound; [79,271): BcatT1; [271,351): BcatT2;
// [351,1680): degree count + epos; [1680,1696): zero out.
__global__ __launch_bounds__(256) void pre1_kernel(
        const int* __restrict__ bidx, int* __restrict__ gstart,
        const float* __restrict__ W1, const float* __restrict__ Wskip,
        const float* __restrict__ W2,
        const float* __restrict__ as1, const float* __restrict__ ad1,
        const float* __restrict__ as2, const float* __restrict__ ad2,
        _Float16* __restrict__ BT1, _Float16* __restrict__ BT2,
        const int* __restrict__ ei, int* __restrict__ deg, int* __restrict__ epos,
        float* __restrict__ outz) {
    int b = blockIdx.x, t = threadIdx.x;
    if (b < 79) {
        int i = b * 256 + t;
        if (i >= NN) return;
        int cur = bidx[i];
        if (i == 0) { for (int g = 0; g <= cur; ++g) gstart[g] = 0; }
        else { int prev = bidx[i - 1]; for (int g = prev + 1; g <= cur; ++g) gstart[g] = i; }
        if (i == NN - 1) { for (int g = cur + 1; g <= GG; ++g) gstart[g] = NN; }
    } else if (b < 271) {
        int i = (b - 79) * 256 + t;          // i < S1*FIN = 49152; BT1[col][k]
        int col = i >> 7, k = i & 127;
        float v;
        if (col < 256) {
            v = W1[k * 256 + (col & 3) * 64 + (col >> 2)];
        } else if (col < 320) {
            v = Wskip[k * 64 + (col - 256)];
        } else if (col < 328) {
            int kk = col - 320, h = kk & 3;
            const float* av = (kk < 4 ? as1 : ad1) + h * 64;
            const float* wr = W1 + k * 256 + h * 64;
            float s = 0.f;
            #pragma unroll 8
            for (int c = 0; c < 64; ++c) s += wr[c] * av[c];
            v = s;
        } else v = 0.f;
        BT1[i] = (_Float16)v;
    } else if (b < 351) {
        int i = (b - 271) * 256 + t;         // i < S2*CC = 20480; BT2[col][k]
        int col = i >> 6, k = i & 63;
        float v;
        if (col < 256) {
            v = W2[k * 256 + (col & 3) * 64 + (col >> 2)];
        } else if (col < 264) {
            int kk = col - 256, h = kk & 3;
            const float* av = (kk < 4 ? as2 : ad2) + h * 64;
            const float* wr = W2 + k * 256 + h * 64;
            float s = 0.f;
            #pragma unroll 8
            for (int c = 0; c < 64; ++c) s += wr[c] * av[c];
            v = s;
        } else v = 0.f;
        BT2[i] = (_Float16)v;
    } else if (b < 1680) {
        int i = (b - 351) * 256 + t;
        if (i >= ETOT) return;
        int d = (i < EE) ? ei[EE + i] : (i - EE);
        epos[i] = atomicAdd(&deg[d], 1);
    } else {
        int i = (b - 1680) * 256 + t;        // i < GG*CC = 4096
        outz[i] = 0.f;
    }
}

// ---------------- CSR fill (no atomics: position precomputed) ----------------------
__global__ void fill_kernel(const int* __restrict__ ei, const int* __restrict__ off,
        const int* __restrict__ epos, int* __restrict__ csr_src) {
    int i = blockIdx.x * 256 + threadIdx.x;
    if (i >= ETOT) return;
    int s, d;
    if (i < EE) { s = ei[i]; d = ei[EE + i]; } else { s = i - EE; d = i - EE; }
    csr_src[off[d] + epos[i]] = s;
}

// ====== fused MFMA fp16 GEMM (1D grid) + optional scan block ======================
// blocks [0, ntiles*313): GEMM tiles (tile = b % ntiles, rowblk = b / ntiles);
// if do_scan: block ntiles*313 runs the 256-thread two-pass exclusive scan.
__global__ __launch_bounds__(256) void gemm_mfma(const float* __restrict__ A,
        const _Float16* __restrict__ BT, int M, int K, int ntiles,
        unsigned short* __restrict__ h4b, float* __restrict__ skipO,
        float* __restrict__ esf, float* __restrict__ edf,
        int skip_tile, int esed_tile, int do_scan,
        const int* __restrict__ deg, int* __restrict__ off) {
    int b = blockIdx.x;
    int t = threadIdx.x;
    if (do_scan && b == ntiles * 313) {
        // two-pass scan: 256 threads x 79 contiguous elems
        const int CH = 79;                 // 256*79 = 20224 >= NN
        __shared__ int bs[256];
        int base = t * CH;
        int sum = 0;
        for (int j = 0; j < CH; ++j) {
            int i = base + j;
            sum += (i < NN) ? deg[i] : 0;
        }
        bs[t] = sum; __syncthreads();
        for (int s = 1; s < 256; s <<= 1) {
            int x = (t >= s) ? bs[t - s] : 0;
            __syncthreads(); bs[t] += x; __syncthreads();
        }
        int run = (t == 0) ? 0 : bs[t - 1];
        for (int j = 0; j < CH; ++j) {
            int i = base + j;
            if (i < NN) { off[i] = run; run += deg[i]; }
        }
        if (t == 255) off[NN] = ETOT;
        return;
    }
    __shared__ _Float16 sA[64][40];    // [row][k], 16B-aligned rows
    __shared__ _Float16 sBT[64][40];   // [col][k]
    int tile = b % ntiles;
    int col0 = tile * 64;
    int row0 = (b / ntiles) * 64;
    int wave = t >> 6, lane = t & 63;
    int l15 = lane & 15, quad = lane >> 4;
    v4f acc[4] = {};
    for (int k0 = 0; k0 < K; k0 += 32) {
        {
            int r = t >> 2, c8 = t & 3;
            int gr = row0 + r;
            float4 v0 = make_float4(0.f, 0.f, 0.f, 0.f);
            float4 v1 = make_float4(0.f, 0.f, 0.f, 0.f);
            if (gr < M) {
                v0 = *(const float4*)&A[(size_t)gr * K + k0 + c8 * 8];
                v1 = *(const float4*)&A[(size_t)gr * K + k0 + c8 * 8 + 4];
            }
            v8h hv;
            hv[0] = (_Float16)v0.x; hv[1] = (_Float16)v0.y;
            hv[2] = (_Float16)v0.z; hv[3] = (_Float16)v0.w;
            hv[4] = (_Float16)v1.x; hv[5] = (_Float16)v1.y;
            hv[6] = (_Float16)v1.z; hv[7] = (_Float16)v1.w;
            *(v8h*)&sA[r][c8 * 8] = hv;
        }
        {
            int c = t >> 2, seg = t & 3;
            v8h v = *(const v8h*)&BT[(size_t)(col0 + c) * K + k0 + seg * 8];
            *(v8h*)&sBT[c][seg * 8] = v;
        }
        __syncthreads();
        v8h af = *(const v8h*)&sA[wave * 16 + l15][quad * 8];
        #pragma unroll
        for (int ct = 0; ct < 4; ++ct) {
            v8h bf = *(const v8h*)&sBT[ct * 16 + l15][quad * 8];
            acc[ct] = __builtin_amdgcn_mfma_f32_16x16x32_f16(af, bf, acc[ct], 0, 0, 0);
        }
        __syncthreads();
    }
    // epilogue: lane holds D[row=quad*4+reg][col=l15] of each 16x16 subtile
    if (tile < 4) {
        #pragma unroll
        for (int ct = 0; ct < 4; ++ct) {
            #pragma unroll
            for (int reg = 0; reg < 4; ++reg) {
                int gr = row0 + wave * 16 + quad * 4 + reg;
                if (gr < M)
                    h4b[(size_t)gr * HC + col0 + ct * 16 + l15] = f2bf(acc[ct][reg]);
            }
        }
    } else if (tile == skip_tile) {
        #pragma unroll
        for (int ct = 0; ct < 4; ++ct) {
            #pragma unroll
            for (int reg = 0; reg < 4; ++reg) {
                int gr = row0 + wave * 16 + quad * 4 + reg;
                if (gr < M)
                    skipO[(size_t)gr * CC + ct * 16 + l15] = acc[ct][reg];
            }
        }
    } else if (tile == esed_tile) {
        if (l15 < 8) {
            #pragma unroll
            for (int reg = 0; reg < 4; ++reg) {
                int gr = row0 + wave * 16 + quad * 4 + reg;
                if (gr < M) {
                    if (l15 < 4) esf[gr * 4 + l15] = acc[0][reg];
                    else         edf[gr * 4 + (l15 - 4)] = acc[0][reg];
                }
            }
        }
    }
}

// ====== aggregation + fused BN statistics ==========================================
__device__ __forceinline__ void edge_acc(const float4 esv, const ushort4 hv,
        const float4 edn, float4& acc, float4& ssum) {
    float e0 = esv.x + edn.x; e0 = fmaxf(e0, 0.2f * e0); float w0 = __expf(e0);
    float e1 = esv.y + edn.y; e1 = fmaxf(e1, 0.2f * e1); float w1 = __expf(e1);
    float e2 = esv.z + edn.z; e2 = fmaxf(e2, 0.2f * e2); float w2 = __expf(e2);
    float e3 = esv.w + edn.w; e3 = fmaxf(e3, 0.2f * e3); float w3 = __expf(e3);
    acc.x += w0 * bf2f(hv.x); ssum.x += w0;
    acc.y += w1 * bf2f(hv.y); ssum.y += w1;
    acc.z += w2 * bf2f(hv.z); ssum.z += w2;
    acc.w += w3 * bf2f(hv.w); ssum.w += w3;
}

// grid = NN/4 = 5000 blocks exactly (NN % 4 == 0): no inactive waves.
__global__ __launch_bounds__(256) void aggr_kernel(const unsigned short* __restrict__ h4b,
        const float4* __restrict__ es4, const float4* __restrict__ ed4,
        const int* __restrict__ off, const int* __restrict__ csr_src,
        const float* __restrict__ bias, float* __restrict__ out,
        float* __restrict__ stats) {
    int wave = threadIdx.x >> 6, lane = threadIdx.x & 63;
    int n = blockIdx.x * 4 + wave;
    float4 edn = ed4[n];
    float4 acc = make_float4(0.f, 0.f, 0.f, 0.f);
    float4 ssum = make_float4(0.f, 0.f, 0.f, 0.f);
    int beg = off[n], end = off[n + 1];
    int j = beg;
    for (; j + 4 <= end; j += 4) {
        int s0 = csr_src[j + 0];
        int s1 = csr_src[j + 1];
        int s2 = csr_src[j + 2];
        int s3 = csr_src[j + 3];
        float4 E0 = es4[s0];
        float4 E1 = es4[s1];
        float4 E2 = es4[s2];
        float4 E3 = es4[s3];
        ushort4 v0 = *(const ushort4*)&h4b[(size_t)s0 * HC + lane * 4];
        ushort4 v1 = *(const ushort4*)&h4b[(size_t)s1 * HC + lane * 4];
        ushort4 v2 = *(const ushort4*)&h4b[(size_t)s2 * HC + lane * 4];
        ushort4 v3 = *(const ushort4*)&h4b[(size_t)s3 * HC + lane * 4];
        edge_acc(E0, v0, edn, acc, ssum);
        edge_acc(E1, v1, edn, acc, ssum);
        edge_acc(E2, v2, edn, acc, ssum);
        edge_acc(E3, v3, edn, acc, ssum);
    }
    for (; j < end; ++j) {
        int s = csr_src[j];
        float4 E = es4[s];
        ushort4 v = *(const ushort4*)&h4b[(size_t)s * HC + lane * 4];
        edge_acc(E, v, edn, acc, ssum);
    }
    float val = 0.25f * (acc.x / (ssum.x + 1e-16f) + acc.y / (ssum.y + 1e-16f) +
                         acc.z / (ssum.z + 1e-16f) + acc.w / (ssum.w + 1e-16f)) + bias[lane];
    out[n * CC + lane] = val;
    // fused BN partial statistics: block-reduce 4 rows, 2 atomics per lane
    __shared__ float ls[4][64], lq[4][64];
    ls[wave][lane] = val;
    lq[wave][lane] = val * val;
    __syncthreads();
    if (wave == 0) {
        float s = ls[0][lane] + ls[1][lane] + ls[2][lane] + ls[3][lane];
        float q = lq[0][lane] + lq[1][lane] + lq[2][lane] + lq[3][lane];
        atomicAdd(&stats[lane], s);
        atomicAdd(&stats[CC + lane], q);
    }
}

// ---------------- BN apply, layer 1 ----------------
__global__ __launch_bounds__(256) void bnapply1_kernel(const float* __restrict__ gout,
        const float* __restrict__ stats, const float* __restrict__ g,
        const float* __restrict__ be, const float* __restrict__ skip,
        const float* __restrict__ bskip, float* __restrict__ outm) {
    int i = blockIdx.x * 256 + threadIdx.x;
    if (i >= NN * CC) return;
    int ch = i & 63;
    float mu  = stats[ch] * (1.f / NN);
    float var = stats[CC + ch] * (1.f / NN) - mu * mu;
    float inv = rsqrtf(var + BN_EPS);
    float v = (gout[i] - mu) * inv * g[ch] + be[ch] + skip[i] + bskip[ch];
    outm[i] = gelu_exact(v);
}

// ---------------- BN apply, layer 2 + fused mean-pool (atomics into zeroed out) ---
__global__ __launch_bounds__(256) void bnapply2_kernel(const float* __restrict__ gout,
        const float* __restrict__ stats, const float* __restrict__ g,
        const float* __restrict__ be, const float* __restrict__ resid,
        const int* __restrict__ bidx, const int* __restrict__ gstart,
        float* __restrict__ out) {
    int i = blockIdx.x * 256 + threadIdx.x;
    if (i >= NN * CC) return;
    int ch = i & 63;
    int n = i >> 6;
    float mu  = stats[ch] * (1.f / NN);
    float var = stats[CC + ch] * (1.f / NN) - mu * mu;
    float inv = rsqrtf(var + BN_EPS);
    float v = (gout[i] - mu) * inv * g[ch] + be[ch] + resid[i];
    v = gelu_exact(v);
    int gg = bidx[n];
    int cnt = gstart[gg + 1] - gstart[gg];     // >= 1 whenever this n exists
    atomicAdd(&out[gg * CC + ch], v * (1.f / (float)cnt));
}

extern "C" void kernel_launch(void* const* d_in, const int* in_sizes, int n_in,
                              void* d_out, int out_size, void* d_ws, size_t ws_size,
                              hipStream_t stream) {
    const float* x      = (const float*)d_in[0];
    const float* W1     = (const float*)d_in[1];
    const float* a_src1 = (const float*)d_in[2];
    const float* a_dst1 = (const float*)d_in[3];
    const float* b1     = (const float*)d_in[4];
    const float* Wskip  = (const float*)d_in[5];
    const float* bskip  = (const float*)d_in[6];
    const float* g1     = (const float*)d_in[7];
    const float* be1    = (const float*)d_in[8];
    const float* W2     = (const float*)d_in[9];
    const float* a_src2 = (const float*)d_in[10];
    const float* a_dst2 = (const float*)d_in[11];
    const float* b2     = (const float*)d_in[12];
    const float* g2     = (const float*)d_in[13];
    const float* be2    = (const float*)d_in[14];
    const int*   ei     = (const int*)d_in[15];
    const int*   bidx   = (const int*)d_in[16];
    float* out = (float*)d_out;

    char* w = (char*)d_ws;
    size_t o = 0;
    auto alloc = [&](size_t bytes) -> void* {
        void* p = w + o;
        o = (o + bytes + 255) & ~(size_t)255;
        return p;
    };

    unsigned short* h4b = (unsigned short*)alloc((size_t)NN * HC * 2);  // bf16 [N][C][H]
    float4* es4 = (float4*)alloc((size_t)NN * 16);
    float4* ed4 = (float4*)alloc((size_t)NN * 16);
    float* skip = (float*)alloc((size_t)NN * CC * 4);
    float* gout = (float*)alloc((size_t)NN * CC * 4);
    float* hmid = (float*)alloc((size_t)NN * CC * 4);
    _Float16* BT1 = (_Float16*)alloc((size_t)S1 * FIN * 2);
    _Float16* BT2 = (_Float16*)alloc((size_t)S2 * CC * 2);
    int* off    = (int*)alloc((size_t)(NN + 1) * 4);
    int* csr    = (int*)alloc((size_t)ETOT * 4);
    int* epos   = (int*)alloc((size_t)ETOT * 4);
    int* gstart = (int*)alloc((size_t)(GG + 1) * 4);
    // ---- zero region (contiguous) ----
    char* zbase = w + o;
    int* deg    = (int*)alloc((size_t)NN * 4);
    float* stats1 = (float*)alloc(128 * 4);
    float* stats2 = (float*)alloc(128 * 4);
    size_t zbytes = (size_t)((w + o) - zbase);

    hipMemsetAsync(zbase, 0, zbytes, stream);

    int ebk = (ETOT + 255) / 256;   // 1329
    int nodeblk = NN / 4;           // 5000 (NN % 4 == 0)

    // ---- pre: gbound | BcatT1 | BcatT2 | count+epos | zero out ----
    pre1_kernel<<<79 + 192 + 80 + ebk + 16, 256, 0, stream>>>(bidx, gstart,
            W1, Wskip, W2, a_src1, a_dst1, a_src2, a_dst2, BT1, BT2, ei, deg, epos,
            out);

    // ---- layer 1 GEMM (+ scan block) ----
    gemm_mfma<<<6 * 313 + 1, 256, 0, stream>>>(x, BT1, NN, FIN, 6,
            h4b, skip, (float*)es4, (float*)ed4, 4, 5, 1, deg, off);
    // ---- CSR fill ----
    fill_kernel<<<ebk, 256, 0, stream>>>(ei, off, epos, csr);
    // ---- layer 1 aggregation (+BN stats) ----
    aggr_kernel<<<nodeblk, 256, 0, stream>>>(h4b, es4, ed4, off, csr, b1, gout,
            stats1);
    bnapply1_kernel<<<(NN * CC + 255) / 256, 256, 0, stream>>>(
        gout, stats1, g1, be1, skip, bskip, hmid);

    // ---- layer 2 ----
    gemm_mfma<<<5 * 313, 256, 0, stream>>>(hmid, BT2, NN, CC, 5,
            h4b, (float*)nullptr, (float*)es4, (float*)ed4, -1, 4, 0,
            (const int*)nullptr, (int*)nullptr);
    aggr_kernel<<<nodeblk, 256, 0, stream>>>(h4b, es4, ed4, off, csr, b2, gout,
            stats2);
    bnapply2_kernel<<<(NN * CC + 255) / 256, 256, 0, stream>>>(
        gout, stats2, g2, be2, hmid, bidx, gstart, out);
}

// Round 13
// 252.868 us; speedup vs baseline: 1.7875x; 1.7875x over previous
//
#include <hip/hip_runtime.h>
#include <math.h>

#define NN   20000
#define EE   320000
#define ETOT 340000
#define FIN  128
#define HH   4
#define CC   64
#define HC   256
#define GG   64
#define BN_EPS 1e-5f
#define S1   384   // BcatT1 cols: 256 (W1 perm) + 64 (Wskip) + 8 (es/ed) + 56 pad
#define S2   320   // BcatT2 cols: 256 (W2 perm) + 8 (es/ed) + 56 pad
#define NBUCK 64   // BN-stats buckets (contention: 5000/64 ~ 78 adds/address)

typedef _Float16 v8h __attribute__((ext_vector_type(8)));
typedef float    v4f __attribute__((ext_vector_type(4)));

__device__ __forceinline__ unsigned short f2bf(float f) {
    unsigned u = __float_as_uint(f);
    unsigned r = (u + 0x7FFF + ((u >> 16) & 1)) >> 16;   // RNE
    return (unsigned short)r;
}
__device__ __forceinline__ float bf2f(unsigned short u) {
    return __uint_as_float((unsigned)u << 16);
}
__device__ __forceinline__ float gelu_exact(float v) {
    return 0.5f * v * (1.f + erff(v * 0.70710678118654752f));
}

// ====== pre1: gbound | BcatT1 | BcatT2 | count+epos | zero d_out ==================
__global__ __launch_bounds__(256) void pre1_kernel(
        const int* __restrict__ bidx, int* __restrict__ gstart,
        const float* __restrict__ W1, const float* __restrict__ Wskip,
        const float* __restrict__ W2,
        const float* __restrict__ as1, const float* __restrict__ ad1,
        const float* __restrict__ as2, const float* __restrict__ ad2,
        _Float16* __restrict__ BT1, _Float16* __restrict__ BT2,
        const int* __restrict__ ei, int* __restrict__ deg, int* __restrict__ epos,
        float* __restrict__ outz) {
    int b = blockIdx.x, t = threadIdx.x;
    if (b < 79) {
        int i = b * 256 + t;
        if (i >= NN) return;
        int cur = bidx[i];
        if (i == 0) { for (int g = 0; g <= cur; ++g) gstart[g] = 0; }
        else { int prev = bidx[i - 1]; for (int g = prev + 1; g <= cur; ++g) gstart[g] = i; }
        if (i == NN - 1) { for (int g = cur + 1; g <= GG; ++g) gstart[g] = NN; }
    } else if (b < 271) {
        int i = (b - 79) * 256 + t;          // i < S1*FIN = 49152; BT1[col][k]
        int col = i >> 7, k = i & 127;
        float v;
        if (col < 256) {
            v = W1[k * 256 + (col & 3) * 64 + (col >> 2)];
        } else if (col < 320) {
            v = Wskip[k * 64 + (col - 256)];
        } else if (col < 328) {
            int kk = col - 320, h = kk & 3;
            const float* av = (kk < 4 ? as1 : ad1) + h * 64;
            const float* wr = W1 + k * 256 + h * 64;
            float s = 0.f;
            #pragma unroll 8
            for (int c = 0; c < 64; ++c) s += wr[c] * av[c];
            v = s;
        } else v = 0.f;
        BT1[i] = (_Float16)v;
    } else if (b < 351) {
        int i = (b - 271) * 256 + t;         // i < S2*CC = 20480; BT2[col][k]
        int col = i >> 6, k = i & 63;
        float v;
        if (col < 256) {
            v = W2[k * 256 + (col & 3) * 64 + (col >> 2)];
        } else if (col < 264) {
            int kk = col - 256, h = kk & 3;
            const float* av = (kk < 4 ? as2 : ad2) + h * 64;
            const float* wr = W2 + k * 256 + h * 64;
            float s = 0.f;
            #pragma unroll 8
            for (int c = 0; c < 64; ++c) s += wr[c] * av[c];
            v = s;
        } else v = 0.f;
        BT2[i] = (_Float16)v;
    } else if (b < 1680) {
        int i = (b - 351) * 256 + t;
        if (i >= ETOT) return;
        int d = (i < EE) ? ei[EE + i] : (i - EE);
        epos[i] = atomicAdd(&deg[d], 1);
    } else {
        int i = (b - 1680) * 256 + t;        // i < GG*CC = 4096
        outz[i] = 0.f;
    }
}

// ---------------- CSR fill (no atomics: position precomputed) ----------------------
__global__ void fill_kernel(const int* __restrict__ ei, const int* __restrict__ off,
        const int* __restrict__ epos, int* __restrict__ csr_src) {
    int i = blockIdx.x * 256 + threadIdx.x;
    if (i >= ETOT) return;
    int s, d;
    if (i < EE) { s = ei[i]; d = ei[EE + i]; } else { s = i - EE; d = i - EE; }
    csr_src[off[d] + epos[i]] = s;
}

// ====== fused MFMA fp16 GEMM (1D grid) + optional scan block ======================
__global__ __launch_bounds__(256) void gemm_mfma(const float* __restrict__ A,
        const _Float16* __restrict__ BT, int M, int K, int ntiles,
        unsigned short* __restrict__ h4b, float* __restrict__ skipO,
        float* __restrict__ esf, float* __restrict__ edf,
        int skip_tile, int esed_tile, int do_scan,
        const int* __restrict__ deg, int* __restrict__ off) {
    int b = blockIdx.x;
    int t = threadIdx.x;
    if (do_scan && b == ntiles * 313) {
        const int CH = 79;                 // 256*79 = 20224 >= NN
        __shared__ int bs[256];
        int base = t * CH;
        int sum = 0;
        for (int j = 0; j < CH; ++j) {
            int i = base + j;
            sum += (i < NN) ? deg[i] : 0;
        }
        bs[t] = sum; __syncthreads();
        for (int s = 1; s < 256; s <<= 1) {
            int x = (t >= s) ? bs[t - s] : 0;
            __syncthreads(); bs[t] += x; __syncthreads();
        }
        int run = (t == 0) ? 0 : bs[t - 1];
        for (int j = 0; j < CH; ++j) {
            int i = base + j;
            if (i < NN) { off[i] = run; run += deg[i]; }
        }
        if (t == 255) off[NN] = ETOT;
        return;
    }
    __shared__ _Float16 sA[64][40];    // [row][k], 16B-aligned rows
    __shared__ _Float16 sBT[64][40];   // [col][k]
    int tile = b % ntiles;
    int col0 = tile * 64;
    int row0 = (b / ntiles) * 64;
    int wave = t >> 6, lane = t & 63;
    int l15 = lane & 15, quad = lane >> 4;
    v4f acc[4] = {};
    for (int k0 = 0; k0 < K; k0 += 32) {
        {
            int r = t >> 2, c8 = t & 3;
            int gr = row0 + r;
            float4 v0 = make_float4(0.f, 0.f, 0.f, 0.f);
            float4 v1 = make_float4(0.f, 0.f, 0.f, 0.f);
            if (gr < M) {
                v0 = *(const float4*)&A[(size_t)gr * K + k0 + c8 * 8];
                v1 = *(const float4*)&A[(size_t)gr * K + k0 + c8 * 8 + 4];
            }
            v8h hv;
            hv[0] = (_Float16)v0.x; hv[1] = (_Float16)v0.y;
            hv[2] = (_Float16)v0.z; hv[3] = (_Float16)v0.w;
            hv[4] = (_Float16)v1.x; hv[5] = (_Float16)v1.y;
            hv[6] = (_Float16)v1.z; hv[7] = (_Float16)v1.w;
            *(v8h*)&sA[r][c8 * 8] = hv;
        }
        {
            int c = t >> 2, seg = t & 3;
            v8h v = *(const v8h*)&BT[(size_t)(col0 + c) * K + k0 + seg * 8];
            *(v8h*)&sBT[c][seg * 8] = v;
        }
        __syncthreads();
        v8h af = *(const v8h*)&sA[wave * 16 + l15][quad * 8];
        #pragma unroll
        for (int ct = 0; ct < 4; ++ct) {
            v8h bf = *(const v8h*)&sBT[ct * 16 + l15][quad * 8];
            acc[ct] = __builtin_amdgcn_mfma_f32_16x16x32_f16(af, bf, acc[ct], 0, 0, 0);
        }
        __syncthreads();
    }
    // epilogue: lane holds D[row=quad*4+reg][col=l15] of each 16x16 subtile
    if (tile < 4) {
        #pragma unroll
        for (int ct = 0; ct < 4; ++ct) {
            #pragma unroll
            for (int reg = 0; reg < 4; ++reg) {
                int gr = row0 + wave * 16 + quad * 4 + reg;
                if (gr < M)
                    h4b[(size_t)gr * HC + col0 + ct * 16 + l15] = f2bf(acc[ct][reg]);
            }
        }
    } else if (tile == skip_tile) {
        #pragma unroll
        for (int ct = 0; ct < 4; ++ct) {
            #pragma unroll
            for (int reg = 0; reg < 4; ++reg) {
                int gr = row0 + wave * 16 + quad * 4 + reg;
                if (gr < M)
                    skipO[(size_t)gr * CC + ct * 16 + l15] = acc[ct][reg];
            }
        }
    } else if (tile == esed_tile) {
        if (l15 < 8) {
            #pragma unroll
            for (int reg = 0; reg < 4; ++reg) {
                int gr = row0 + wave * 16 + quad * 4 + reg;
                if (gr < M) {
                    if (l15 < 4) esf[gr * 4 + l15] = acc[0][reg];
                    else         edf[gr * 4 + (l15 - 4)] = acc[0][reg];
                }
            }
        }
    }
}

// ====== aggregation + fused BN statistics (bucketed atomics) =======================
__device__ __forceinline__ void edge_acc(const float4 esv, const ushort4 hv,
        const float4 edn, float4& acc, float4& ssum) {
    float e0 = esv.x + edn.x; e0 = fmaxf(e0, 0.2f * e0); float w0 = __expf(e0);
    float e1 = esv.y + edn.y; e1 = fmaxf(e1, 0.2f * e1); float w1 = __expf(e1);
    float e2 = esv.z + edn.z; e2 = fmaxf(e2, 0.2f * e2); float w2 = __expf(e2);
    float e3 = esv.w + edn.w; e3 = fmaxf(e3, 0.2f * e3); float w3 = __expf(e3);
    acc.x += w0 * bf2f(hv.x); ssum.x += w0;
    acc.y += w1 * bf2f(hv.y); ssum.y += w1;
    acc.z += w2 * bf2f(hv.z); ssum.z += w2;
    acc.w += w3 * bf2f(hv.w); ssum.w += w3;
}

// grid = NN/4 = 5000 blocks exactly.
__global__ __launch_bounds__(256) void aggr_kernel(const unsigned short* __restrict__ h4b,
        const float4* __restrict__ es4, const float4* __restrict__ ed4,
        const int* __restrict__ off, const int* __restrict__ csr_src,
        const float* __restrict__ bias, float* __restrict__ out,
        float* __restrict__ sbuck) {
    int wave = threadIdx.x >> 6, lane = threadIdx.x & 63;
    int n = blockIdx.x * 4 + wave;
    float4 edn = ed4[n];
    float4 acc = make_float4(0.f, 0.f, 0.f, 0.f);
    float4 ssum = make_float4(0.f, 0.f, 0.f, 0.f);
    int beg = off[n], end = off[n + 1];
    int j = beg;
    for (; j + 4 <= end; j += 4) {
        int s0 = csr_src[j + 0];
        int s1 = csr_src[j + 1];
        int s2 = csr_src[j + 2];
        int s3 = csr_src[j + 3];
        float4 E0 = es4[s0];
        float4 E1 = es4[s1];
        float4 E2 = es4[s2];
        float4 E3 = es4[s3];
        ushort4 v0 = *(const ushort4*)&h4b[(size_t)s0 * HC + lane * 4];
        ushort4 v1 = *(const ushort4*)&h4b[(size_t)s1 * HC + lane * 4];
        ushort4 v2 = *(const ushort4*)&h4b[(size_t)s2 * HC + lane * 4];
        ushort4 v3 = *(const ushort4*)&h4b[(size_t)s3 * HC + lane * 4];
        edge_acc(E0, v0, edn, acc, ssum);
        edge_acc(E1, v1, edn, acc, ssum);
        edge_acc(E2, v2, edn, acc, ssum);
        edge_acc(E3, v3, edn, acc, ssum);
    }
    for (; j < end; ++j) {
        int s = csr_src[j];
        float4 E = es4[s];
        ushort4 v = *(const ushort4*)&h4b[(size_t)s * HC + lane * 4];
        edge_acc(E, v, edn, acc, ssum);
    }
    float val = 0.25f * (acc.x / (ssum.x + 1e-16f) + acc.y / (ssum.y + 1e-16f) +
                         acc.z / (ssum.z + 1e-16f) + acc.w / (ssum.w + 1e-16f)) + bias[lane];
    out[n * CC + lane] = val;
    // fused BN partials: block-reduce 4 rows, then 2 atomics/lane into this block's
    // bucket (64 buckets -> ~78 same-address adds, not 5000: R12's 132-us lesson)
    __shared__ float ls[4][64], lq[4][64];
    ls[wave][lane] = val;
    lq[wave][lane] = val * val;
    __syncthreads();
    if (wave == 0) {
        float s = ls[0][lane] + ls[1][lane] + ls[2][lane] + ls[3][lane];
        float q = lq[0][lane] + lq[1][lane] + lq[2][lane] + lq[3][lane];
        int bk = (blockIdx.x & (NBUCK - 1)) * 128;
        atomicAdd(&sbuck[bk + lane], s);
        atomicAdd(&sbuck[bk + 64 + lane], q);
    }
}

// ---------------- BN apply, layer 1 (bucket reduction in LDS prologue) -------------
__global__ __launch_bounds__(256) void bnapply1_kernel(const float* __restrict__ gout,
        const float* __restrict__ sbuck, const float* __restrict__ g,
        const float* __restrict__ be, const float* __restrict__ skip,
        const float* __restrict__ bskip, float* __restrict__ outm) {
    __shared__ float tmp[128];
    __shared__ float smu[64], sinv[64];
    int t = threadIdx.x;
    if (t < 128) {
        float s = 0.f;
        #pragma unroll 16
        for (int k = 0; k < NBUCK; ++k) s += sbuck[k * 128 + t];
        tmp[t] = s;
    }
    __syncthreads();
    if (t < 64) {
        float mu  = tmp[t] * (1.f / NN);
        float var = tmp[64 + t] * (1.f / NN) - mu * mu;
        smu[t] = mu;
        sinv[t] = rsqrtf(var + BN_EPS) * g[t];
    }
    __syncthreads();
    int i = blockIdx.x * 256 + t;          // grid exact: NN*CC/256
    int ch = i & 63;
    float v = (gout[i] - smu[ch]) * sinv[ch] + be[ch] + skip[i] + bskip[ch];
    outm[i] = gelu_exact(v);
}

// ---------------- BN apply, layer 2 + fused mean-pool (4-node combined atomics) ----
__global__ __launch_bounds__(256) void bnapply2_kernel(const float* __restrict__ gout,
        const float* __restrict__ sbuck, const float* __restrict__ g,
        const float* __restrict__ be, const float* __restrict__ resid,
        const int* __restrict__ bidx, const int* __restrict__ gstart,
        float* __restrict__ out) {
    __shared__ float tmp[128];
    __shared__ float smu[64], sinv[64];
    __shared__ float ls[4][64];
    __shared__ int gi[4];
    int t = threadIdx.x;
    if (t < 128) {
        float s = 0.f;
        #pragma unroll 16
        for (int k = 0; k < NBUCK; ++k) s += sbuck[k * 128 + t];
        tmp[t] = s;
    }
    __syncthreads();
    if (t < 64) {
        float mu  = tmp[t] * (1.f / NN);
        float var = tmp[64 + t] * (1.f / NN) - mu * mu;
        smu[t] = mu;
        sinv[t] = rsqrtf(var + BN_EPS) * g[t];
    }
    __syncthreads();
    int i = blockIdx.x * 256 + t;          // grid exact: 5000 blocks, 4 nodes each
    int ch = i & 63;
    int wave = t >> 6;
    int n = i >> 6;
    float v = (gout[i] - smu[ch]) * sinv[ch] + be[ch] + resid[i];
    v = gelu_exact(v);
    int gg = bidx[n];
    int cnt = gstart[gg + 1] - gstart[gg];
    ls[wave][ch] = v * (1.f / (float)cnt);
    if (ch == 0) gi[wave] = gg;
    __syncthreads();
    if (wave == 0) {
        if (gi[0] == gi[1] && gi[1] == gi[2] && gi[2] == gi[3]) {
            float s = ls[0][ch] + ls[1][ch] + ls[2][ch] + ls[3][ch];
            atomicAdd(&out[gi[0] * CC + ch], s);
        } else {
            #pragma unroll
            for (int w2 = 0; w2 < 4; ++w2)
                atomicAdd(&out[gi[w2] * CC + ch], ls[w2][ch]);
        }
    }
}

extern "C" void kernel_launch(void* const* d_in, const int* in_sizes, int n_in,
                              void* d_out, int out_size, void* d_ws, size_t ws_size,
                              hipStream_t stream) {
    const float* x      = (const float*)d_in[0];
    const float* W1     = (const float*)d_in[1];
    const float* a_src1 = (const float*)d_in[2];
    const float* a_dst1 = (const float*)d_in[3];
    const float* b1     = (const float*)d_in[4];
    const float* Wskip  = (const float*)d_in[5];
    const float* bskip  = (const float*)d_in[6];
    const float* g1     = (const float*)d_in[7];
    const float* be1    = (const float*)d_in[8];
    const float* W2     = (const float*)d_in[9];
    const float* a_src2 = (const float*)d_in[10];
    const float* a_dst2 = (const float*)d_in[11];
    const float* b2     = (const float*)d_in[12];
    const float* g2     = (const float*)d_in[13];
    const float* be2    = (const float*)d_in[14];
    const int*   ei     = (const int*)d_in[15];
    const int*   bidx   = (const int*)d_in[16];
    float* out = (float*)d_out;

    char* w = (char*)d_ws;
    size_t o = 0;
    auto alloc = [&](size_t bytes) -> void* {
        void* p = w + o;
        o = (o + bytes + 255) & ~(size_t)255;
        return p;
    };

    unsigned short* h4b = (unsigned short*)alloc((size_t)NN * HC * 2);  // bf16 [N][C][H]
    float4* es4 = (float4*)alloc((size_t)NN * 16);
    float4* ed4 = (float4*)alloc((size_t)NN * 16);
    float* skip = (float*)alloc((size_t)NN * CC * 4);
    float* gout = (float*)alloc((size_t)NN * CC * 4);
    float* hmid = (float*)alloc((size_t)NN * CC * 4);
    _Float16* BT1 = (_Float16*)alloc((size_t)S1 * FIN * 2);
    _Float16* BT2 = (_Float16*)alloc((size_t)S2 * CC * 2);
    int* off    = (int*)alloc((size_t)(NN + 1) * 4);
    int* csr    = (int*)alloc((size_t)ETOT * 4);
    int* epos   = (int*)alloc((size_t)ETOT * 4);
    int* gstart = (int*)alloc((size_t)(GG + 1) * 4);
    // ---- zero region (contiguous) ----
    char* zbase = w + o;
    int* deg      = (int*)alloc((size_t)NN * 4);
    float* sbuck1 = (float*)alloc((size_t)NBUCK * 128 * 4);
    float* sbuck2 = (float*)alloc((size_t)NBUCK * 128 * 4);
    size_t zbytes = (size_t)((w + o) - zbase);

    hipMemsetAsync(zbase, 0, zbytes, stream);

    int ebk = (ETOT + 255) / 256;   // 1329
    int nodeblk = NN / 4;           // 5000 (NN % 4 == 0)

    // ---- pre: gbound | BcatT1 | BcatT2 | count+epos | zero out ----
    pre1_kernel<<<79 + 192 + 80 + ebk + 16, 256, 0, stream>>>(bidx, gstart,
            W1, Wskip, W2, a_src1, a_dst1, a_src2, a_dst2, BT1, BT2, ei, deg, epos,
            out);

    // ---- layer 1 GEMM (+ scan block) ----
    gemm_mfma<<<6 * 313 + 1, 256, 0, stream>>>(x, BT1, NN, FIN, 6,
            h4b, skip, (float*)es4, (float*)ed4, 4, 5, 1, deg, off);
    // ---- CSR fill ----
    fill_kernel<<<ebk, 256, 0, stream>>>(ei, off, epos, csr);
    // ---- layer 1 aggregation (+bucketed BN stats) ----
    aggr_kernel<<<nodeblk, 256, 0, stream>>>(h4b, es4, ed4, off, csr, b1, gout,
            sbuck1);
    bnapply1_kernel<<<NN * CC / 256, 256, 0, stream>>>(
        gout, sbuck1, g1, be1, skip, bskip, hmid);

    // ---- layer 2 ----
    gemm_mfma<<<5 * 313, 256, 0, stream>>>(hmid, BT2, NN, CC, 5,
            h4b, (float*)nullptr, (float*)es4, (float*)ed4, -1, 4, 0,
            (const int*)nullptr, (int*)nullptr);
    aggr_kernel<<<nodeblk, 256, 0, stream>>>(h4b, es4, ed4, off, csr, b2, gout,
            sbuck2);
    bnapply2_kernel<<<NN * CC / 256, 256, 0, stream>>>(
        gout, sbuck2, g2, be2, hmid, bidx, gstart, out);
}

// Round 14
// 249.115 us; speedup vs baseline: 1.8144x; 1.0151x over previous
//
#include <hip/hip_runtime.h>
#include <math.h>

#define NN   20000
#define EE   320000
#define ETOT 340000
#define FIN  128
#define HH   4
#define CC   64
#define HC   256
#define GG   64
#define BN_EPS 1e-5f
#define S1   384   // BcatT1 cols: 256 (W1 perm) + 64 (Wskip) + 8 (es/ed) + 56 pad
#define S2   320   // BcatT2 cols: 256 (W2 perm) + 8 (es/ed) + 56 pad
#define NBUCK 64   // BN-stats buckets (contention: 5000/64 ~ 78 adds/address)

typedef _Float16 v8h __attribute__((ext_vector_type(8)));
typedef float    v4f __attribute__((ext_vector_type(4)));

__device__ __forceinline__ unsigned short f2bf(float f) {
    unsigned u = __float_as_uint(f);
    unsigned r = (u + 0x7FFF + ((u >> 16) & 1)) >> 16;   // RNE
    return (unsigned short)r;
}
__device__ __forceinline__ float bf2f(unsigned short u) {
    return __uint_as_float((unsigned)u << 16);
}
__device__ __forceinline__ float gelu_exact(float v) {
    return 0.5f * v * (1.f + erff(v * 0.70710678118654752f));
}

// ====== pre1: gbound | BcatT1 | BcatT2 | count+epos | zero d_out ==================
__global__ __launch_bounds__(256) void pre1_kernel(
        const int* __restrict__ bidx, int* __restrict__ gstart,
        const float* __restrict__ W1, const float* __restrict__ Wskip,
        const float* __restrict__ W2,
        const float* __restrict__ as1, const float* __restrict__ ad1,
        const float* __restrict__ as2, const float* __restrict__ ad2,
        _Float16* __restrict__ BT1, _Float16* __restrict__ BT2,
        const int* __restrict__ ei, int* __restrict__ deg, int* __restrict__ epos,
        float* __restrict__ outz) {
    int b = blockIdx.x, t = threadIdx.x;
    if (b < 79) {
        int i = b * 256 + t;
        if (i >= NN) return;
        int cur = bidx[i];
        if (i == 0) { for (int g = 0; g <= cur; ++g) gstart[g] = 0; }
        else { int prev = bidx[i - 1]; for (int g = prev + 1; g <= cur; ++g) gstart[g] = i; }
        if (i == NN - 1) { for (int g = cur + 1; g <= GG; ++g) gstart[g] = NN; }
    } else if (b < 271) {
        int i = (b - 79) * 256 + t;          // i < S1*FIN = 49152; BT1[col][k]
        int col = i >> 7, k = i & 127;
        float v;
        if (col < 256) {
            v = W1[k * 256 + (col & 3) * 64 + (col >> 2)];
        } else if (col < 320) {
            v = Wskip[k * 64 + (col - 256)];
        } else if (col < 328) {
            int kk = col - 320, h = kk & 3;
            const float* av = (kk < 4 ? as1 : ad1) + h * 64;
            const float* wr = W1 + k * 256 + h * 64;
            float s = 0.f;
            #pragma unroll 8
            for (int c = 0; c < 64; ++c) s += wr[c] * av[c];
            v = s;
        } else v = 0.f;
        BT1[i] = (_Float16)v;
    } else if (b < 351) {
        int i = (b - 271) * 256 + t;         // i < S2*CC = 20480; BT2[col][k]
        int col = i >> 6, k = i & 63;
        float v;
        if (col < 256) {
            v = W2[k * 256 + (col & 3) * 64 + (col >> 2)];
        } else if (col < 264) {
            int kk = col - 256, h = kk & 3;
            const float* av = (kk < 4 ? as2 : ad2) + h * 64;
            const float* wr = W2 + k * 256 + h * 64;
            float s = 0.f;
            #pragma unroll 8
            for (int c = 0; c < 64; ++c) s += wr[c] * av[c];
            v = s;
        } else v = 0.f;
        BT2[i] = (_Float16)v;
    } else if (b < 1680) {
        int i = (b - 351) * 256 + t;
        if (i >= ETOT) return;
        int d = (i < EE) ? ei[EE + i] : (i - EE);
        epos[i] = atomicAdd(&deg[d], 1);
    } else {
        int i = (b - 1680) * 256 + t;        // i < GG*CC = 4096
        outz[i] = 0.f;
    }
}

// ---------------- CSR fill (no atomics: position precomputed) ----------------------
__global__ void fill_kernel(const int* __restrict__ ei, const int* __restrict__ off,
        const int* __restrict__ epos, int* __restrict__ csr_src) {
    int i = blockIdx.x * 256 + threadIdx.x;
    if (i >= ETOT) return;
    int s, d;
    if (i < EE) { s = ei[i]; d = ei[EE + i]; } else { s = i - EE; d = i - EE; }
    csr_src[off[d] + epos[i]] = s;
}

// ====== fused MFMA fp16 GEMM, wide tiles ==========================================
// Block = 64 rows x (2*NCB*16) cols; 2 col-tiles span the whole B. Wave covers
// 2 row-frags x NCB col-frags -> 2+NCB ds_reads feed 2*NCB MFMAs per K-chunk
// (R13's 4-MFMA-per-barrier kernel was latency-bound: MfmaUtil 1.5%).
// Epilogue routes each global col: [0,256)->h4b bf16; [256,320)&&skipO->skip fp32;
// [escol0,escol0+8)->es/ed. If do_scan, block 626 runs the exclusive deg-scan.
template<int NCB>
__global__ __launch_bounds__(256) void gemm_mfma(const float* __restrict__ A,
        const _Float16* __restrict__ BT, int M, int K,
        unsigned short* __restrict__ h4b, float* __restrict__ skipO,
        float* __restrict__ esf, float* __restrict__ edf,
        int escol0, int do_scan,
        const int* __restrict__ deg, int* __restrict__ off) {
    int b = blockIdx.x;
    int t = threadIdx.x;
    if (do_scan && b == 626) {
        const int CH = 79;                 // 256*79 = 20224 >= NN
        __shared__ int bs[256];
        int base = t * CH;
        int sum = 0;
        for (int j = 0; j < CH; ++j) {
            int i = base + j;
            sum += (i < NN) ? deg[i] : 0;
        }
        bs[t] = sum; __syncthreads();
        for (int s = 1; s < 256; s <<= 1) {
            int x = (t >= s) ? bs[t - s] : 0;
            __syncthreads(); bs[t] += x; __syncthreads();
        }
        int run = (t == 0) ? 0 : bs[t - 1];
        for (int j = 0; j < CH; ++j) {
            int i = base + j;
            if (i < NN) { off[i] = run; run += deg[i]; }
        }
        if (t == 255) off[NN] = ETOT;
        return;
    }
    const int COLT = 2 * NCB * 16;         // 192 (gemm1) / 160 (gemm2)
    __shared__ _Float16 sA[64][40];        // [row][k], stride 80B: 2-way = free
    __shared__ _Float16 sBT[2 * NCB * 16][40];
    int tile = b & 1;
    int col0 = tile * COLT;
    int row0 = (b >> 1) * 64;
    int wave = t >> 6, lane = t & 63;
    int l15 = lane & 15, quad = lane >> 4;
    int rb0 = (wave >> 1) * 2;             // this wave's 2 row-frags
    int cb0 = (wave & 1) * NCB;            // this wave's NCB col-frags
    v4f acc[2][NCB] = {};
    for (int k0 = 0; k0 < K; k0 += 32) {
        {   // stage A: 64 rows x 32 k, fp32 -> fp16
            int r = t >> 2, c8 = t & 3;
            int gr = row0 + r;
            float4 v0 = make_float4(0.f, 0.f, 0.f, 0.f);
            float4 v1 = make_float4(0.f, 0.f, 0.f, 0.f);
            if (gr < M) {
                v0 = *(const float4*)&A[(size_t)gr * K + k0 + c8 * 8];
                v1 = *(const float4*)&A[(size_t)gr * K + k0 + c8 * 8 + 4];
            }
            v8h hv;
            hv[0] = (_Float16)v0.x; hv[1] = (_Float16)v0.y;
            hv[2] = (_Float16)v0.z; hv[3] = (_Float16)v0.w;
            hv[4] = (_Float16)v1.x; hv[5] = (_Float16)v1.y;
            hv[6] = (_Float16)v1.z; hv[7] = (_Float16)v1.w;
            *(v8h*)&sA[r][c8 * 8] = hv;
        }
        // stage BT: COLT cols x 32 k (fp16, contiguous in k)
        for (int j = t; j < COLT * 4; j += 256) {
            int c = j >> 2, s = j & 3;
            *(v8h*)&sBT[c][s * 8] = *(const v8h*)&BT[(size_t)(col0 + c) * K + k0 + s * 8];
        }
        __syncthreads();
        v8h af0 = *(const v8h*)&sA[(rb0 + 0) * 16 + l15][quad * 8];
        v8h af1 = *(const v8h*)&sA[(rb0 + 1) * 16 + l15][quad * 8];
        #pragma unroll
        for (int c = 0; c < NCB; ++c) {
            v8h bf = *(const v8h*)&sBT[(cb0 + c) * 16 + l15][quad * 8];
            acc[0][c] = __builtin_amdgcn_mfma_f32_16x16x32_f16(af0, bf, acc[0][c], 0, 0, 0);
            acc[1][c] = __builtin_amdgcn_mfma_f32_16x16x32_f16(af1, bf, acc[1][c], 0, 0, 0);
        }
        __syncthreads();
    }
    // epilogue: D[row=quad*4+reg][col=l15] per 16x16 frag (verified mapping)
    #pragma unroll
    for (int rr = 0; rr < 2; ++rr) {
        #pragma unroll
        for (int c = 0; c < NCB; ++c) {
            int gcol = col0 + (cb0 + c) * 16 + l15;
            #pragma unroll
            for (int reg = 0; reg < 4; ++reg) {
                int gr = row0 + (rb0 + rr) * 16 + quad * 4 + reg;
                if (gr >= M) continue;
                float v = acc[rr][c][reg];
                if (gcol < 256) {
                    h4b[(size_t)gr * HC + gcol] = f2bf(v);
                } else if (skipO != nullptr && gcol < 320) {
                    skipO[(size_t)gr * CC + (gcol - 256)] = v;
                } else if (gcol >= escol0 && gcol < escol0 + 8) {
                    if (gcol < escol0 + 4) esf[gr * 4 + (gcol - escol0)] = v;
                    else                   edf[gr * 4 + (gcol - escol0 - 4)] = v;
                }
            }
        }
    }
}

// ====== aggregation + fused BN statistics (bucketed atomics) =======================
__device__ __forceinline__ void edge_acc(const float4 esv, const ushort4 hv,
        const float4 edn, float4& acc, float4& ssum) {
    float e0 = esv.x + edn.x; e0 = fmaxf(e0, 0.2f * e0); float w0 = __expf(e0);
    float e1 = esv.y + edn.y; e1 = fmaxf(e1, 0.2f * e1); float w1 = __expf(e1);
    float e2 = esv.z + edn.z; e2 = fmaxf(e2, 0.2f * e2); float w2 = __expf(e2);
    float e3 = esv.w + edn.w; e3 = fmaxf(e3, 0.2f * e3); float w3 = __expf(e3);
    acc.x += w0 * bf2f(hv.x); ssum.x += w0;
    acc.y += w1 * bf2f(hv.y); ssum.y += w1;
    acc.z += w2 * bf2f(hv.z); ssum.z += w2;
    acc.w += w3 * bf2f(hv.w); ssum.w += w3;
}

// grid = NN/4 = 5000 blocks exactly.
__global__ __launch_bounds__(256) void aggr_kernel(const unsigned short* __restrict__ h4b,
        const float4* __restrict__ es4, const float4* __restrict__ ed4,
        const int* __restrict__ off, const int* __restrict__ csr_src,
        const float* __restrict__ bias, float* __restrict__ out,
        float* __restrict__ sbuck) {
    int wave = threadIdx.x >> 6, lane = threadIdx.x & 63;
    int n = blockIdx.x * 4 + wave;
    float4 edn = ed4[n];
    float4 acc = make_float4(0.f, 0.f, 0.f, 0.f);
    float4 ssum = make_float4(0.f, 0.f, 0.f, 0.f);
    int beg = off[n], end = off[n + 1];
    int j = beg;
    for (; j + 4 <= end; j += 4) {
        int s0 = csr_src[j + 0];
        int s1 = csr_src[j + 1];
        int s2 = csr_src[j + 2];
        int s3 = csr_src[j + 3];
        float4 E0 = es4[s0];
        float4 E1 = es4[s1];
        float4 E2 = es4[s2];
        float4 E3 = es4[s3];
        ushort4 v0 = *(const ushort4*)&h4b[(size_t)s0 * HC + lane * 4];
        ushort4 v1 = *(const ushort4*)&h4b[(size_t)s1 * HC + lane * 4];
        ushort4 v2 = *(const ushort4*)&h4b[(size_t)s2 * HC + lane * 4];
        ushort4 v3 = *(const ushort4*)&h4b[(size_t)s3 * HC + lane * 4];
        edge_acc(E0, v0, edn, acc, ssum);
        edge_acc(E1, v1, edn, acc, ssum);
        edge_acc(E2, v2, edn, acc, ssum);
        edge_acc(E3, v3, edn, acc, ssum);
    }
    for (; j < end; ++j) {
        int s = csr_src[j];
        float4 E = es4[s];
        ushort4 v = *(const ushort4*)&h4b[(size_t)s * HC + lane * 4];
        edge_acc(E, v, edn, acc, ssum);
    }
    float val = 0.25f * (acc.x / (ssum.x + 1e-16f) + acc.y / (ssum.y + 1e-16f) +
                         acc.z / (ssum.z + 1e-16f) + acc.w / (ssum.w + 1e-16f)) + bias[lane];
    out[n * CC + lane] = val;
    // fused BN partials: block-reduce 4 rows, then 2 atomics/lane into this block's
    // bucket (64 buckets -> ~78 same-address adds, not 5000: R12's 132-us lesson)
    __shared__ float ls[4][64], lq[4][64];
    ls[wave][lane] = val;
    lq[wave][lane] = val * val;
    __syncthreads();
    if (wave == 0) {
        float s = ls[0][lane] + ls[1][lane] + ls[2][lane] + ls[3][lane];
        float q = lq[0][lane] + lq[1][lane] + lq[2][lane] + lq[3][lane];
        int bk = (blockIdx.x & (NBUCK - 1)) * 128;
        atomicAdd(&sbuck[bk + lane], s);
        atomicAdd(&sbuck[bk + 64 + lane], q);
    }
}

// ---------------- BN apply, layer 1 (bucket reduction in LDS prologue) -------------
__global__ __launch_bounds__(256) void bnapply1_kernel(const float* __restrict__ gout,
        const float* __restrict__ sbuck, const float* __restrict__ g,
        const float* __restrict__ be, const float* __restrict__ skip,
        const float* __restrict__ bskip, float* __restrict__ outm) {
    __shared__ float tmp[128];
    __shared__ float smu[64], sinv[64];
    int t = threadIdx.x;
    if (t < 128) {
        float s = 0.f;
        #pragma unroll 16
        for (int k = 0; k < NBUCK; ++k) s += sbuck[k * 128 + t];
        tmp[t] = s;
    }
    __syncthreads();
    if (t < 64) {
        float mu  = tmp[t] * (1.f / NN);
        float var = tmp[64 + t] * (1.f / NN) - mu * mu;
        smu[t] = mu;
        sinv[t] = rsqrtf(var + BN_EPS) * g[t];
    }
    __syncthreads();
    int i = blockIdx.x * 256 + t;          // grid exact: NN*CC/256
    int ch = i & 63;
    float v = (gout[i] - smu[ch]) * sinv[ch] + be[ch] + skip[i] + bskip[ch];
    outm[i] = gelu_exact(v);
}

// ---------------- BN apply, layer 2 + fused mean-pool (4-node combined atomics) ----
__global__ __launch_bounds__(256) void bnapply2_kernel(const float* __restrict__ gout,
        const float* __restrict__ sbuck, const float* __restrict__ g,
        const float* __restrict__ be, const float* __restrict__ resid,
        const int* __restrict__ bidx, const int* __restrict__ gstart,
        float* __restrict__ out) {
    __shared__ float tmp[128];
    __shared__ float smu[64], sinv[64];
    __shared__ float ls[4][64];
    __shared__ int gi[4];
    int t = threadIdx.x;
    if (t < 128) {
        float s = 0.f;
        #pragma unroll 16
        for (int k = 0; k < NBUCK; ++k) s += sbuck[k * 128 + t];
        tmp[t] = s;
    }
    __syncthreads();
    if (t < 64) {
        float mu  = tmp[t] * (1.f / NN);
        float var = tmp[64 + t] * (1.f / NN) - mu * mu;
        smu[t] = mu;
        sinv[t] = rsqrtf(var + BN_EPS) * g[t];
    }
    __syncthreads();
    int i = blockIdx.x * 256 + t;          // grid exact: 5000 blocks, 4 nodes each
    int ch = i & 63;
    int wave = t >> 6;
    int n = i >> 6;
    float v = (gout[i] - smu[ch]) * sinv[ch] + be[ch] + resid[i];
    v = gelu_exact(v);
    int gg = bidx[n];
    int cnt = gstart[gg + 1] - gstart[gg];
    ls[wave][ch] = v * (1.f / (float)cnt);
    if (ch == 0) gi[wave] = gg;
    __syncthreads();
    if (wave == 0) {
        if (gi[0] == gi[1] && gi[1] == gi[2] && gi[2] == gi[3]) {
            float s = ls[0][ch] + ls[1][ch] + ls[2][ch] + ls[3][ch];
            atomicAdd(&out[gi[0] * CC + ch], s);
        } else {
            #pragma unroll
            for (int w2 = 0; w2 < 4; ++w2)
                atomicAdd(&out[gi[w2] * CC + ch], ls[w2][ch]);
        }
    }
}

extern "C" void kernel_launch(void* const* d_in, const int* in_sizes, int n_in,
                              void* d_out, int out_size, void* d_ws, size_t ws_size,
                              hipStream_t stream) {
    const float* x      = (const float*)d_in[0];
    const float* W1     = (const float*)d_in[1];
    const float* a_src1 = (const float*)d_in[2];
    const float* a_dst1 = (const float*)d_in[3];
    const float* b1     = (const float*)d_in[4];
    const float* Wskip  = (const float*)d_in[5];
    const float* bskip  = (const float*)d_in[6];
    const float* g1     = (const float*)d_in[7];
    const float* be1    = (const float*)d_in[8];
    const float* W2     = (const float*)d_in[9];
    const float* a_src2 = (const float*)d_in[10];
    const float* a_dst2 = (const float*)d_in[11];
    const float* b2     = (const float*)d_in[12];
    const float* g2     = (const float*)d_in[13];
    const float* be2    = (const float*)d_in[14];
    const int*   ei     = (const int*)d_in[15];
    const int*   bidx   = (const int*)d_in[16];
    float* out = (float*)d_out;

    char* w = (char*)d_ws;
    size_t o = 0;
    auto alloc = [&](size_t bytes) -> void* {
        void* p = w + o;
        o = (o + bytes + 255) & ~(size_t)255;
        return p;
    };

    unsigned short* h4b = (unsigned short*)alloc((size_t)NN * HC * 2);  // bf16 [N][C][H]
    float4* es4 = (float4*)alloc((size_t)NN * 16);
    float4* ed4 = (float4*)alloc((size_t)NN * 16);
    float* skip = (float*)alloc((size_t)NN * CC * 4);
    float* gout = (float*)alloc((size_t)NN * CC * 4);
    float* hmid = (float*)alloc((size_t)NN * CC * 4);
    _Float16* BT1 = (_Float16*)alloc((size_t)S1 * FIN * 2);
    _Float16* BT2 = (_Float16*)alloc((size_t)S2 * CC * 2);
    int* off    = (int*)alloc((size_t)(NN + 1) * 4);
    int* csr    = (int*)alloc((size_t)ETOT * 4);
    int* epos   = (int*)alloc((size_t)ETOT * 4);
    int* gstart = (int*)alloc((size_t)(GG + 1) * 4);
    // ---- zero region (contiguous) ----
    char* zbase = w + o;
    int* deg      = (int*)alloc((size_t)NN * 4);
    float* sbuck1 = (float*)alloc((size_t)NBUCK * 128 * 4);
    float* sbuck2 = (float*)alloc((size_t)NBUCK * 128 * 4);
    size_t zbytes = (size_t)((w + o) - zbase);

    hipMemsetAsync(zbase, 0, zbytes, stream);

    int ebk = (ETOT + 255) / 256;   // 1329
    int nodeblk = NN / 4;           // 5000 (NN % 4 == 0)

    // ---- pre: gbound | BcatT1 | BcatT2 | count+epos | zero out ----
    pre1_kernel<<<79 + 192 + 80 + ebk + 16, 256, 0, stream>>>(bidx, gstart,
            W1, Wskip, W2, a_src1, a_dst1, a_src2, a_dst2, BT1, BT2, ei, deg, epos,
            out);

    // ---- layer 1 GEMM: 2 x 192-col tiles (+ scan block at b==626) ----
    gemm_mfma<6><<<627, 256, 0, stream>>>(x, BT1, NN, FIN,
            h4b, skip, (float*)es4, (float*)ed4, 320, 1, deg, off);
    // ---- CSR fill ----
    fill_kernel<<<ebk, 256, 0, stream>>>(ei, off, epos, csr);
    // ---- layer 1 aggregation (+bucketed BN stats) ----
    aggr_kernel<<<nodeblk, 256, 0, stream>>>(h4b, es4, ed4, off, csr, b1, gout,
            sbuck1);
    bnapply1_kernel<<<NN * CC / 256, 256, 0, stream>>>(
        gout, sbuck1, g1, be1, skip, bskip, hmid);

    // ---- layer 2 GEMM: 2 x 160-col tiles ----
    gemm_mfma<5><<<626, 256, 0, stream>>>(hmid, BT2, NN, CC,
            h4b, (float*)nullptr, (float*)es4, (float*)ed4, 256, 0,
            (const int*)nullptr, (int*)nullptr);
    aggr_kernel<<<nodeblk, 256, 0, stream>>>(h4b, es4, ed4, off, csr, b2, gout,
            sbuck2);
    bnapply2_kernel<<<NN * CC / 256, 256, 0, stream>>>(
        gout, sbuck2, g2, be2, hmid, bidx, gstart, out);
}